// Round 6
// baseline (245.157 us; speedup 1.0000x reference)
//
#include <hip/hip_runtime.h>

// Problem constants
#define Bc   2
#define Sc   1024
#define Hc   2048
#define NHc  16
#define NKVc 4
#define HDc  128
#define KBc  1024
#define NREPc 4

typedef unsigned short ushort_t;
typedef unsigned int uint32;
typedef __attribute__((ext_vector_type(8))) __bf16 bf16x8;
typedef __attribute__((ext_vector_type(4))) float f32x4;

static __device__ __forceinline__ size_t dsz(int x) { return (size_t)x; }

static __device__ __forceinline__ ushort_t f2bf(float f) {
  uint32 u = __float_as_uint(f);
  u += 0x7fffu + ((u >> 16) & 1u);        // round-to-nearest-even
  return (ushort_t)(u >> 16);
}
static __device__ __forceinline__ float bf2f(ushort_t u) {
  return __uint_as_float(((uint32)u) << 16);
}

#define ROPE_INV 0.14391156831212787f   // ln(10000)/64
#define QSCALE   (0.08838834764831845f * 1.4426950408889634f)  // scale*log2e

// ---------------------------------------------------------------------------
// Fused fp32 -> bf16 conversion of all 6 inputs (one dispatch).
// ---------------------------------------------------------------------------
#define FSEG 1048576
__global__ void conv_all(const float* __restrict__ x,  const float* __restrict__ Wq,
                         const float* __restrict__ Wqn, const float* __restrict__ Wk,
                         const float* __restrict__ Wv,  const float* __restrict__ Wo,
                         ushort_t* xb, ushort_t* Wqb, ushort_t* Wqnb,
                         ushort_t* Wkb, ushort_t* Wvb, ushort_t* Wob)
{
  int i = blockIdx.x * 256 + threadIdx.x;      // f4 index, < 4.5*FSEG
  const float* s; ushort_t* d; int off;
  if      (i <     FSEG)            { s = x;   d = xb;   off = i; }
  else if (i < 2 * FSEG)            { s = Wq;  d = Wqb;  off = i - FSEG; }
  else if (i < 3 * FSEG)            { s = Wqn; d = Wqnb; off = i - 2 * FSEG; }
  else if (i < 3 * FSEG + FSEG / 4) { s = Wk;  d = Wkb;  off = i - 3 * FSEG; }
  else if (i < 3 * FSEG + FSEG / 2) { s = Wv;  d = Wvb;  off = i - 3 * FSEG - FSEG / 4; }
  else                              { s = Wo;  d = Wob;  off = i - 3 * FSEG - FSEG / 2; }
  float4 v = ((const float4*)s)[off];
  ushort4 o;
  o.x = f2bf(v.x); o.y = f2bf(v.y); o.z = f2bf(v.z); o.w = f2bf(v.w);
  ((ushort4*)d)[off] = o;
}

// ---------------------------------------------------------------------------
// global_load_lds helper
// ---------------------------------------------------------------------------
#define GL16(gsrc, ldst)                                                \
  __builtin_amdgcn_global_load_lds(                                     \
      (const __attribute__((address_space(1))) void*)(gsrc),            \
      (__attribute__((address_space(3))) void*)(ldst), 16, 0, 0)

// ---------------------------------------------------------------------------
// Fused projection GEMM (one dispatch, 640 blocks): C = xb * W^T for
// {Wq->qb, Wqn->qnb(*QSCALE), Wk->kkvb, Wv->vkvb}, bf16 outputs.
// ---------------------------------------------------------------------------
__global__ __launch_bounds__(256) void gemm_proj(
    const ushort_t* __restrict__ A,    // xb [2048][2048]
    const ushort_t* __restrict__ Wqb,  const ushort_t* __restrict__ Wqnb,
    const ushort_t* __restrict__ Wkb,  const ushort_t* __restrict__ Wvb,
    ushort_t* __restrict__ qb, ushort_t* __restrict__ qnb,
    ushort_t* __restrict__ kkvb, ushort_t* __restrict__ vkvb)
{
  __shared__ ushort_t sA[128 * 32];
  __shared__ ushort_t sB[128 * 32];

  const int K = Hc;                    // 2048
  const int bx = blockIdx.x;
  const ushort_t* Bseg; ushort_t* Cseg; int segN, colseg; float scale;
  if      (bx < 16) { Bseg = Wqb;  Cseg = qb;   segN = 2048; colseg = bx * 128;        scale = 1.f; }
  else if (bx < 32) { Bseg = Wqnb; Cseg = qnb;  segN = 2048; colseg = (bx - 16) * 128; scale = QSCALE; }
  else if (bx < 36) { Bseg = Wkb;  Cseg = kkvb; segN = 512;  colseg = (bx - 32) * 128; scale = 1.f; }
  else              { Bseg = Wvb;  Cseg = vkvb; segN = 512;  colseg = (bx - 36) * 128; scale = 1.f; }

  const int tid  = threadIdx.x;
  const int lane = tid & 63;
  const int wid  = tid >> 6;
  const int wr   = wid >> 1;
  const int wc   = wid & 1;
  const int row0 = blockIdx.y * 128;
  const int fr = lane & 15;
  const int fq = lane >> 4;

  f32x4 acc[4][4];
  #pragma unroll
  for (int m = 0; m < 4; ++m)
    #pragma unroll
    for (int n = 0; n < 4; ++n) acc[m][n] = (f32x4){0.f, 0.f, 0.f, 0.f};

  const int rS = tid >> 2;
  const int kg = (tid & 3) * 8;
  const ushort_t* Asrc0 = A + dsz(row0 + rS) * K + kg;
  const ushort_t* Asrc1 = A + dsz(row0 + 64 + rS) * K + kg;
  const ushort_t* Bsrc0 = Bseg + dsz(colseg + rS) * K + kg;
  const ushort_t* Bsrc1 = Bseg + dsz(colseg + 64 + rS) * K + kg;
  char* ldsA0 = (char*)sA + tid * 16;
  char* ldsA1 = (char*)sA + 4096 + tid * 16;
  char* ldsB0 = (char*)sB + tid * 16;
  char* ldsB1 = (char*)sB + 4096 + tid * 16;

  for (int k0 = 0; k0 < K; k0 += 32) {
    GL16(Asrc0 + k0, ldsA0);
    GL16(Asrc1 + k0, ldsA1);
    GL16(Bsrc0 + k0, ldsB0);
    GL16(Bsrc1 + k0, ldsB1);
    __syncthreads();

    bf16x8 a[4], b[4];
    #pragma unroll
    for (int m = 0; m < 4; ++m)
      a[m] = *(const bf16x8*)&sA[(wr * 64 + m * 16 + fr) * 32 + fq * 8];
    #pragma unroll
    for (int n = 0; n < 4; ++n)
      b[n] = *(const bf16x8*)&sB[(wc * 64 + n * 16 + fr) * 32 + fq * 8];
    #pragma unroll
    for (int m = 0; m < 4; ++m)
      #pragma unroll
      for (int n = 0; n < 4; ++n)
        acc[m][n] = __builtin_amdgcn_mfma_f32_16x16x32_bf16(a[m], b[n], acc[m][n], 0, 0, 0);
    __syncthreads();
  }

  #pragma unroll
  for (int m = 0; m < 4; ++m)
    #pragma unroll
    for (int n = 0; n < 4; ++n)
      #pragma unroll
      for (int j = 0; j < 4; ++j)
        Cseg[dsz(row0 + wr * 64 + m * 16 + fq * 4 + j) * segN +
             colseg + wc * 64 + n * 16 + fr] = f2bf(acc[m][n][j] * scale);
}

// ---------------------------------------------------------------------------
// Generic bf16 GEMM with f32 output (final Wo projection).
// ---------------------------------------------------------------------------
__global__ __launch_bounds__(256) void gemm_bt_bf16(
    const ushort_t* __restrict__ A, const ushort_t* __restrict__ B,
    float* __restrict__ C, int M, int N, int K)
{
  __shared__ ushort_t sA[128 * 32];
  __shared__ ushort_t sB[128 * 32];

  const int tid  = threadIdx.x;
  const int lane = tid & 63;
  const int wid  = tid >> 6;
  const int wr   = wid >> 1;
  const int wc   = wid & 1;
  const int row0 = blockIdx.y * 128;
  const int col0 = blockIdx.x * 128;
  const int fr = lane & 15;
  const int fq = lane >> 4;

  f32x4 acc[4][4];
  #pragma unroll
  for (int m = 0; m < 4; ++m)
    #pragma unroll
    for (int n = 0; n < 4; ++n) acc[m][n] = (f32x4){0.f, 0.f, 0.f, 0.f};

  const int rS = tid >> 2;
  const int kg = (tid & 3) * 8;
  const ushort_t* Asrc0 = A + dsz(row0 + rS) * K + kg;
  const ushort_t* Asrc1 = A + dsz(row0 + 64 + rS) * K + kg;
  const ushort_t* Bsrc0 = B + dsz(col0 + rS) * K + kg;
  const ushort_t* Bsrc1 = B + dsz(col0 + 64 + rS) * K + kg;
  char* ldsA0 = (char*)sA + tid * 16;
  char* ldsA1 = (char*)sA + 4096 + tid * 16;
  char* ldsB0 = (char*)sB + tid * 16;
  char* ldsB1 = (char*)sB + 4096 + tid * 16;

  for (int k0 = 0; k0 < K; k0 += 32) {
    GL16(Asrc0 + k0, ldsA0);
    GL16(Asrc1 + k0, ldsA1);
    GL16(Bsrc0 + k0, ldsB0);
    GL16(Bsrc1 + k0, ldsB1);
    __syncthreads();

    bf16x8 a[4], b[4];
    #pragma unroll
    for (int m = 0; m < 4; ++m)
      a[m] = *(const bf16x8*)&sA[(wr * 64 + m * 16 + fr) * 32 + fq * 8];
    #pragma unroll
    for (int n = 0; n < 4; ++n)
      b[n] = *(const bf16x8*)&sB[(wc * 64 + n * 16 + fr) * 32 + fq * 8];
    #pragma unroll
    for (int m = 0; m < 4; ++m)
      #pragma unroll
      for (int n = 0; n < 4; ++n)
        acc[m][n] = __builtin_amdgcn_mfma_f32_16x16x32_bf16(a[m], b[n], acc[m][n], 0, 0, 0);
    __syncthreads();
  }

  #pragma unroll
  for (int m = 0; m < 4; ++m)
    #pragma unroll
    for (int n = 0; n < 4; ++n)
      #pragma unroll
      for (int j = 0; j < 4; ++j)
        C[dsz(row0 + wr * 64 + m * 16 + fq * 4 + j) * N +
          col0 + wc * 64 + n * 16 + fr] = acc[m][n][j];
}

// ---------------------------------------------------------------------------
// RoPE in-place on bf16 qb, folds in QSCALE.
// ---------------------------------------------------------------------------
__global__ void rope_q_ip(ushort_t* __restrict__ qb, const int* __restrict__ pos)
{
  int idx = blockIdx.x * blockDim.x + threadIdx.x;   // 2M
  int j = idx & 63;
  int h = (idx >> 6) & 15;
  int r = idx >> 10;
  float p = (float)pos[r];
  float f = p * expf(-(float)j * ROPE_INV);
  float c = cosf(f), s = sinf(f);
  ushort_t* d = qb + dsz(r) * (NHc * HDc) + h * HDc;
  float x1 = bf2f(d[j]), x2 = bf2f(d[j + 64]);
  d[j]      = f2bf((x1 * c - x2 * s) * QSCALE);
  d[j + 64] = f2bf((x2 * c + x1 * s) * QSCALE);
}

// RoPE self-k (bf16 in) -> Kcat rows 1024..2047
__global__ void rope_k_kcat(const ushort_t* __restrict__ kkvb, const int* __restrict__ pos,
                            ushort_t* __restrict__ Kcat)
{
  int idx = blockIdx.x * blockDim.x + threadIdx.x;   // 512K
  int j = idx & 63;
  int kvh = (idx >> 6) & 3;
  int s = (idx >> 8) & 1023;
  int b = idx >> 18;
  float p = (float)pos[b * Sc + s];
  float f = p * expf(-(float)j * ROPE_INV);
  float c = cosf(f), sn = sinf(f);
  const ushort_t* src = kkvb + dsz(b * Sc + s) * (NKVc * HDc) + kvh * HDc;
  ushort_t* dst = Kcat + (dsz(b * NKVc + kvh) * 2048 + 1024 + s) * HDc;
  float x1 = bf2f(src[j]), x2 = bf2f(src[j + 64]);
  dst[j]      = f2bf(x1 * c - x2 * sn);
  dst[j + 64] = f2bf(x2 * c + x1 * sn);
}

// kb_keys fp32 -> Kcat rows 0..1023 bf16
__global__ void kb_kcat(const float* __restrict__ src, ushort_t* __restrict__ Kcat)
{
  int i = blockIdx.x * blockDim.x + threadIdx.x;     // 262144
  int d4 = i & 31;
  int kvh = (i >> 5) & 3;
  int k = (i >> 7) & 1023;
  int b = i >> 17;
  float4 v = *(const float4*)&src[dsz(b * KBc + k) * (NKVc * HDc) + kvh * HDc + d4 * 4];
  ushort4 o;
  o.x = f2bf(v.x); o.y = f2bf(v.y); o.z = f2bf(v.z); o.w = f2bf(v.w);
  *(ushort4*)&Kcat[(dsz(b * NKVc + kvh) * 2048 + k) * HDc + d4 * 4] = o;
}

// Build Vt[b][kvh][128][2048] from kb_values (f32) + vkvb (bf16)
__global__ __launch_bounds__(256) void vt_build(const float* __restrict__ kbv,
                                                const ushort_t* __restrict__ vkvb,
                                                ushort_t* __restrict__ Vt)
{
  __shared__ float sT[32][33];
  const int k0 = blockIdx.x * 32;
  const int d0 = blockIdx.y * 32;
  const int bk = blockIdx.z;
  const int b = bk >> 2, kvh = bk & 3;
  const int tid = threadIdx.x;

  #pragma unroll
  for (int t = 0; t < 4; ++t) {
    int li = tid + t * 256;
    int kk = li >> 5, dl = li & 31;
    int kg = k0 + kk;
    float v = (kg < 1024)
      ? kbv[dsz(b * KBc + kg) * (NKVc * HDc) + kvh * HDc + d0 + dl]
      : bf2f(vkvb[dsz(b * Sc + kg - 1024) * (NKVc * HDc) + kvh * HDc + d0 + dl]);
    sT[kk][dl] = v;
  }
  __syncthreads();
  #pragma unroll
  for (int t = 0; t < 4; ++t) {
    int li = tid + t * 256;
    int dl = li >> 5, kk = li & 31;
    Vt[(dsz(b * NKVc + kvh) * HDc + d0 + dl) * 2048 + k0 + kk] = f2bf(sT[kk][dl]);
  }
}

// ---------------------------------------------------------------------------
// Attention v4: LDS-staged, double-buffered, 32 queries/wave.
// Block = (b, h, 64 q), 2 waves x 32 q (2 subgroups of 16 sharing K/V frags).
// Conflict-free b128 XOR swizzles: K slot' = slot ^ ((r&3)|((r>>3)<<2)),
// V slot' = slot ^ ((r>>1)&3) -- applied on global source, linear LDS dest.
// ---------------------------------------------------------------------------
__global__ __launch_bounds__(128) void attn_mfma4(
    const ushort_t* __restrict__ Qr,   // roped q (pre-scaled), (B*S, 2048)
    const ushort_t* __restrict__ Qn,   // q_new (pre-scaled), (B*S, 2048)
    const ushort_t* __restrict__ Kcat, // (B, NKV, 2048, 128)
    const ushort_t* __restrict__ Vt,   // (B, NKV, 128, 2048)
    ushort_t* __restrict__ attnb)      // (B*S, 2048)
{
  __shared__ ushort_t sK[2][32 * 128];   // 8KB per buf
  __shared__ ushort_t sV[2][128 * 32];   // 8KB per buf

  const int tid = threadIdx.x;
  const int lane = tid & 63;
  const int w = tid >> 6;                // 0..1
  const int fr = lane & 15;
  const int fq = lane >> 4;              // 0..3
  const int blk = blockIdx.x;
  const int qt = blk & 15;
  const int h  = (blk >> 4) & 15;
  const int b  = blk >> 8;
  const int kvh = h >> 2;
  const int kperm = ((fr >> 2) << 3) + (fr & 3);   // permuted K row (u(kperm)=fr)

  const ushort_t* Kb = Kcat + dsz(b * NKVc + kvh) * 2048 * HDc;
  const ushort_t* Vb = Vt   + dsz(b * NKVc + kvh) * HDc * 2048;

  const int qrow0 = qt * 64 + w * 32 + fr;   // subgroup 0 query
  const int qrow1 = qrow0 + 16;              // subgroup 1 query
  const int vslot = (fq ^ ((fr >> 1) & 3)) * 8;

  const int ntiles = 34 + 2 * qt;            // keys = 1024 + qt*64 + 64

  float m0 = -1e30f, l0 = 0.f, m1 = -1e30f, l1 = 0.f;
  f32x4 ot0[8], ot1[8];
  #pragma unroll
  for (int dt = 0; dt < 8; ++dt) {
    ot0[dt] = (f32x4){0.f, 0.f, 0.f, 0.f};
    ot1[dt] = (f32x4){0.f, 0.f, 0.f, 0.f};
  }

#define STAGE(bi, t)                                                     \
  {                                                                      \
    const char* kgb = (const char*)Kb + (size_t)(t) * 8192;              \
    const char* vgb = (const char*)Vb + (size_t)(t) * 64;                \
    _Pragma("unroll")                                                    \
    for (int cc = 0; cc < 4; ++cc) {                                     \
      int r  = cc * 8 + (tid >> 4);                                      \
      int uu = (r & 3) | ((r >> 3) << 2);                                \
      GL16(kgb + r * 256 + (((tid & 15) ^ uu) * 16),                     \
           (char*)&sK[bi][0] + cc * 2048 + tid * 16);                    \
    }                                                                    \
    _Pragma("unroll")                                                    \
    for (int cc = 0; cc < 4; ++cc) {                                     \
      int r  = cc * 32 + (tid >> 2);                                     \
      int uv = (r >> 1) & 3;                                             \
      GL16(vgb + (size_t)r * 4096 + (((tid & 3) ^ uv) * 16),             \
           (char*)&sV[bi][0] + cc * 2048 + tid * 16);                    \
    }                                                                    \
  }

  // Q fragments: phase 0 (KB keys) uses q_new
  bf16x8 qf0[4], qf1[4];
  {
    const ushort_t* p0 = Qn + dsz(b * Sc + qrow0) * (NHc * HDc) + h * HDc;
    const ushort_t* p1 = Qn + dsz(b * Sc + qrow1) * (NHc * HDc) + h * HDc;
    #pragma unroll
    for (int c = 0; c < 4; ++c) {
      qf0[c] = *(const bf16x8*)&p0[c * 32 + fq * 8];
      qf1[c] = *(const bf16x8*)&p1[c * 32 + fq * 8];
    }
  }

  STAGE(0, 0);
  __syncthreads();

  for (int t = 0; t < ntiles; ++t) {
    const int cur = t & 1;
    if (t + 1 < ntiles) STAGE(cur ^ 1, t + 1);

    if (t == 32) {   // phase switch: self keys use roped q
      const ushort_t* p0 = Qr + dsz(b * Sc + qrow0) * (NHc * HDc) + h * HDc;
      const ushort_t* p1 = Qr + dsz(b * Sc + qrow1) * (NHc * HDc) + h * HDc;
      #pragma unroll
      for (int c = 0; c < 4; ++c) {
        qf0[c] = *(const bf16x8*)&p0[c * 32 + fq * 8];
        qf1[c] = *(const bf16x8*)&p1[c * 32 + fq * 8];
      }
    }
    const bool self = (t >= 32);

    // shared fragments from LDS (un-swizzled on read)
    bf16x8 ka0[4], ka1[4], va[8];
    #pragma unroll
    for (int c = 0; c < 4; ++c) {
      const int ks = ((c * 4 + fq) ^ fr) * 8;
      ka0[c] = *(const bf16x8*)&sK[cur][kperm * 128 + ks];
      ka1[c] = *(const bf16x8*)&sK[cur][(kperm + 4) * 128 + ks];
    }
    #pragma unroll
    for (int dt = 0; dt < 8; ++dt)
      va[dt] = *(const bf16x8*)&sV[cur][(dt * 16 + fr) * 32 + vslot];

    // ---- subgroup 0 ----
    {
      f32x4 s0 = (f32x4){0.f, 0.f, 0.f, 0.f};
      f32x4 s1 = (f32x4){0.f, 0.f, 0.f, 0.f};
      __builtin_amdgcn_s_setprio(1);
      #pragma unroll
      for (int c = 0; c < 4; ++c)
        s0 = __builtin_amdgcn_mfma_f32_16x16x32_bf16(ka0[c], qf0[c], s0, 0, 0, 0);
      #pragma unroll
      for (int c = 0; c < 4; ++c)
        s1 = __builtin_amdgcn_mfma_f32_16x16x32_bf16(ka1[c], qf0[c], s1, 0, 0, 0);
      __builtin_amdgcn_s_setprio(0);
      if (self) {
        #pragma unroll
        for (int j = 0; j < 4; ++j) {
          s0[j] = (t * 32 + fq * 8 + j     - 1024 > qrow0) ? -1e30f : s0[j];
          s1[j] = (t * 32 + fq * 8 + 4 + j - 1024 > qrow0) ? -1e30f : s1[j];
        }
      }
      float tmax = fmaxf(fmaxf(fmaxf(s0[0], s0[1]), fmaxf(s0[2], s0[3])),
                         fmaxf(fmaxf(s1[0], s1[1]), fmaxf(s1[2], s1[3])));
      tmax = fmaxf(tmax, __shfl_xor(tmax, 16));
      tmax = fmaxf(tmax, __shfl_xor(tmax, 32));
      if (__any(tmax > m0 + 8.f)) {
        float mnew = fmaxf(m0, tmax);
        float corr = exp2f(m0 - mnew);
        l0 *= corr;
        #pragma unroll
        for (int dt = 0; dt < 8; ++dt) {
          ot0[dt][0] *= corr; ot0[dt][1] *= corr;
          ot0[dt][2] *= corr; ot0[dt][3] *= corr;
        }
        m0 = mnew;
      }
      float ps = 0.f;
      bf16x8 pb;
      #pragma unroll
      for (int j = 0; j < 4; ++j) { float p = exp2f(s0[j] - m0); ps += p; pb[j] = (__bf16)p; }
      #pragma unroll
      for (int j = 0; j < 4; ++j) { float p = exp2f(s1[j] - m0); ps += p; pb[j + 4] = (__bf16)p; }
      l0 += ps;
      __builtin_amdgcn_s_setprio(1);
      #pragma unroll
      for (int dt = 0; dt < 8; ++dt)
        ot0[dt] = __builtin_amdgcn_mfma_f32_16x16x32_bf16(va[dt], pb, ot0[dt], 0, 0, 0);
      __builtin_amdgcn_s_setprio(0);
    }
    // ---- subgroup 1 ----
    {
      f32x4 s0 = (f32x4){0.f, 0.f, 0.f, 0.f};
      f32x4 s1 = (f32x4){0.f, 0.f, 0.f, 0.f};
      __builtin_amdgcn_s_setprio(1);
      #pragma unroll
      for (int c = 0; c < 4; ++c)
        s0 = __builtin_amdgcn_mfma_f32_16x16x32_bf16(ka0[c], qf1[c], s0, 0, 0, 0);
      #pragma unroll
      for (int c = 0; c < 4; ++c)
        s1 = __builtin_amdgcn_mfma_f32_16x16x32_bf16(ka1[c], qf1[c], s1, 0, 0, 0);
      __builtin_amdgcn_s_setprio(0);
      if (self) {
        #pragma unroll
        for (int j = 0; j < 4; ++j) {
          s0[j] = (t * 32 + fq * 8 + j     - 1024 > qrow1) ? -1e30f : s0[j];
          s1[j] = (t * 32 + fq * 8 + 4 + j - 1024 > qrow1) ? -1e30f : s1[j];
        }
      }
      float tmax = fmaxf(fmaxf(fmaxf(s0[0], s0[1]), fmaxf(s0[2], s0[3])),
                         fmaxf(fmaxf(s1[0], s1[1]), fmaxf(s1[2], s1[3])));
      tmax = fmaxf(tmax, __shfl_xor(tmax, 16));
      tmax = fmaxf(tmax, __shfl_xor(tmax, 32));
      if (__any(tmax > m1 + 8.f)) {
        float mnew = fmaxf(m1, tmax);
        float corr = exp2f(m1 - mnew);
        l1 *= corr;
        #pragma unroll
        for (int dt = 0; dt < 8; ++dt) {
          ot1[dt][0] *= corr; ot1[dt][1] *= corr;
          ot1[dt][2] *= corr; ot1[dt][3] *= corr;
        }
        m1 = mnew;
      }
      float ps = 0.f;
      bf16x8 pb;
      #pragma unroll
      for (int j = 0; j < 4; ++j) { float p = exp2f(s0[j] - m1); ps += p; pb[j] = (__bf16)p; }
      #pragma unroll
      for (int j = 0; j < 4; ++j) { float p = exp2f(s1[j] - m1); ps += p; pb[j + 4] = (__bf16)p; }
      l1 += ps;
      __builtin_amdgcn_s_setprio(1);
      #pragma unroll
      for (int dt = 0; dt < 8; ++dt)
        ot1[dt] = __builtin_amdgcn_mfma_f32_16x16x32_bf16(va[dt], pb, ot1[dt], 0, 0, 0);
      __builtin_amdgcn_s_setprio(0);
    }

    __syncthreads();   // drains staging loads; safe buffer swap
  }
#undef STAGE

  l0 += __shfl_xor(l0, 16); l0 += __shfl_xor(l0, 32);
  l1 += __shfl_xor(l1, 16); l1 += __shfl_xor(l1, 32);
  const float li0 = 1.f / l0;
  const float li1 = 1.f / l1;
  ushort_t* ob0 = attnb + dsz(b * Sc + qrow0) * (NHc * HDc) + h * HDc;
  ushort_t* ob1 = attnb + dsz(b * Sc + qrow1) * (NHc * HDc) + h * HDc;
  #pragma unroll
  for (int dt = 0; dt < 8; ++dt) {
    ushort_t o4a[4];
    #pragma unroll
    for (int j = 0; j < 4; ++j) o4a[j] = f2bf(ot0[dt][j] * li0);
    *(ushort4*)&ob0[dt * 16 + fq * 4] = *(ushort4*)o4a;
    #pragma unroll
    for (int j = 0; j < 4; ++j) o4a[j] = f2bf(ot1[dt][j] * li1);
    *(ushort4*)&ob1[dt * 16 + fq * 4] = *(ushort4*)o4a;
  }
}

// ---------------------------------------------------------------------------
// Launch
// ---------------------------------------------------------------------------
extern "C" void kernel_launch(void* const* d_in, const int* in_sizes, int n_in,
                              void* d_out, int out_size, void* d_ws, size_t ws_size,
                              hipStream_t stream)
{
  const float* x    = (const float*)d_in[0];
  const int*   pos  = (const int*)d_in[2];
  const float* kbk  = (const float*)d_in[3];
  const float* kbv  = (const float*)d_in[4];
  const float* Wq   = (const float*)d_in[5];
  const float* Wqn  = (const float*)d_in[6];
  const float* Wk   = (const float*)d_in[7];
  const float* Wv   = (const float*)d_in[8];
  const float* Wo   = (const float*)d_in[9];
  float* out = (float*)d_out;

  const int MR = Bc * Sc;              // 2048
  const size_t MU = 1048576;

  ushort_t* U = (ushort_t*)d_ws;
  ushort_t* xb    = U;                 // 4M u
  ushort_t* Wqb   = U + 4  * MU;       // 4M
  ushort_t* Wqnb  = U + 8  * MU;       // 4M
  ushort_t* Wkb   = U + 12 * MU;       // 1M
  ushort_t* Wvb   = U + 13 * MU;       // 1M
  ushort_t* Wob   = U + 14 * MU;       // 4M
  ushort_t* qb    = U + 18 * MU;       // 4M (roped in-place -> Qr)
  ushort_t* qnb   = U + 22 * MU;       // 4M (pre-scaled)
  ushort_t* kkvb  = U + 26 * MU;       // 1M
  ushort_t* vkvb  = U + 27 * MU;       // 1M
  ushort_t* Kcat  = U + 28 * MU;       // 2M
  ushort_t* Vt    = U + 30 * MU;       // 2M
  ushort_t* attnb = U + 32 * MU;       // 4M  -> total 36M u = 72 MB

  dim3 blk(256);

  conv_all<<<18432, blk, 0, stream>>>(x, Wq, Wqn, Wk, Wv, Wo,
                                      xb, Wqb, Wqnb, Wkb, Wvb, Wob);
  gemm_proj<<<dim3(40, 16), blk, 0, stream>>>(xb, Wqb, Wqnb, Wkb, Wvb,
                                              qb, qnb, kkvb, vkvb);
  rope_q_ip<<<8192, blk, 0, stream>>>(qb, pos);
  kb_kcat<<<1024, blk, 0, stream>>>(kbk, Kcat);
  rope_k_kcat<<<2048, blk, 0, stream>>>(kkvb, pos, Kcat);
  vt_build<<<dim3(64, 4, 8), blk, 0, stream>>>(kbv, vkvb, Vt);
  // attention: (b,h,64q) blocks, 2 waves x 32q, LDS-staged double-buffered
  attn_mfma4<<<512, dim3(128), 0, stream>>>(qb, qnb, Kcat, Vt, attnb);
  gemm_bt_bf16<<<dim3(16, 16), blk, 0, stream>>>(attnb, Wob, out, MR, 2048, Hc);
}

// Round 7
// 198.266 us; speedup vs baseline: 1.2365x; 1.2365x over previous
//
#include <hip/hip_runtime.h>

// Problem constants
#define Bc   2
#define Sc   1024
#define Hc   2048
#define NHc  16
#define NKVc 4
#define HDc  128
#define KBc  1024
#define NREPc 4

typedef unsigned short ushort_t;
typedef unsigned int uint32;
typedef __attribute__((ext_vector_type(8))) __bf16 bf16x8;
typedef __attribute__((ext_vector_type(4))) float f32x4;

static __device__ __forceinline__ size_t dsz(int x) { return (size_t)x; }

static __device__ __forceinline__ ushort_t f2bf(float f) {
  uint32 u = __float_as_uint(f);
  u += 0x7fffu + ((u >> 16) & 1u);        // round-to-nearest-even
  return (ushort_t)(u >> 16);
}
static __device__ __forceinline__ float bf2f(ushort_t u) {
  return __uint_as_float(((uint32)u) << 16);
}

#define ROPE_INV 0.14391156831212787f   // ln(10000)/64
#define QSCALE   (0.08838834764831845f * 1.4426950408889634f)  // scale*log2e

// ---------------------------------------------------------------------------
// Fused fp32 -> bf16 conversion of all 6 inputs (one dispatch).
// ---------------------------------------------------------------------------
#define FSEG 1048576
__global__ void conv_all(const float* __restrict__ x,  const float* __restrict__ Wq,
                         const float* __restrict__ Wqn, const float* __restrict__ Wk,
                         const float* __restrict__ Wv,  const float* __restrict__ Wo,
                         ushort_t* xb, ushort_t* Wqb, ushort_t* Wqnb,
                         ushort_t* Wkb, ushort_t* Wvb, ushort_t* Wob)
{
  int i = blockIdx.x * 256 + threadIdx.x;      // f4 index, < 4.5*FSEG
  const float* s; ushort_t* d; int off;
  if      (i <     FSEG)            { s = x;   d = xb;   off = i; }
  else if (i < 2 * FSEG)            { s = Wq;  d = Wqb;  off = i - FSEG; }
  else if (i < 3 * FSEG)            { s = Wqn; d = Wqnb; off = i - 2 * FSEG; }
  else if (i < 3 * FSEG + FSEG / 4) { s = Wk;  d = Wkb;  off = i - 3 * FSEG; }
  else if (i < 3 * FSEG + FSEG / 2) { s = Wv;  d = Wvb;  off = i - 3 * FSEG - FSEG / 4; }
  else                              { s = Wo;  d = Wob;  off = i - 3 * FSEG - FSEG / 2; }
  float4 v = ((const float4*)s)[off];
  ushort4 o;
  o.x = f2bf(v.x); o.y = f2bf(v.y); o.z = f2bf(v.z); o.w = f2bf(v.w);
  ((ushort4*)d)[off] = o;
}

// ---------------------------------------------------------------------------
// global_load_lds helper
// ---------------------------------------------------------------------------
#define GL16(gsrc, ldst)                                                \
  __builtin_amdgcn_global_load_lds(                                     \
      (const __attribute__((address_space(1))) void*)(gsrc),            \
      (__attribute__((address_space(3))) void*)(ldst), 16, 0, 0)

// ---------------------------------------------------------------------------
// Fused projection GEMM (one dispatch, 640 blocks): C = xb * W^T for
// {Wq->qb, Wqn->qnb(*QSCALE), Wk->kkvb, Wv->vkvb}, bf16 outputs.
// ---------------------------------------------------------------------------
__global__ __launch_bounds__(256) void gemm_proj(
    const ushort_t* __restrict__ A,    // xb [2048][2048]
    const ushort_t* __restrict__ Wqb,  const ushort_t* __restrict__ Wqnb,
    const ushort_t* __restrict__ Wkb,  const ushort_t* __restrict__ Wvb,
    ushort_t* __restrict__ qb, ushort_t* __restrict__ qnb,
    ushort_t* __restrict__ kkvb, ushort_t* __restrict__ vkvb)
{
  __shared__ ushort_t sA[128 * 32];
  __shared__ ushort_t sB[128 * 32];

  const int K = Hc;                    // 2048
  const int bx = blockIdx.x;
  const ushort_t* Bseg; ushort_t* Cseg; int segN, colseg; float scale;
  if      (bx < 16) { Bseg = Wqb;  Cseg = qb;   segN = 2048; colseg = bx * 128;        scale = 1.f; }
  else if (bx < 32) { Bseg = Wqnb; Cseg = qnb;  segN = 2048; colseg = (bx - 16) * 128; scale = QSCALE; }
  else if (bx < 36) { Bseg = Wkb;  Cseg = kkvb; segN = 512;  colseg = (bx - 32) * 128; scale = 1.f; }
  else              { Bseg = Wvb;  Cseg = vkvb; segN = 512;  colseg = (bx - 36) * 128; scale = 1.f; }

  const int tid  = threadIdx.x;
  const int lane = tid & 63;
  const int wid  = tid >> 6;
  const int wr   = wid >> 1;
  const int wc   = wid & 1;
  const int row0 = blockIdx.y * 128;
  const int fr = lane & 15;
  const int fq = lane >> 4;

  f32x4 acc[4][4];
  #pragma unroll
  for (int m = 0; m < 4; ++m)
    #pragma unroll
    for (int n = 0; n < 4; ++n) acc[m][n] = (f32x4){0.f, 0.f, 0.f, 0.f};

  const int rS = tid >> 2;
  const int kg = (tid & 3) * 8;
  const ushort_t* Asrc0 = A + dsz(row0 + rS) * K + kg;
  const ushort_t* Asrc1 = A + dsz(row0 + 64 + rS) * K + kg;
  const ushort_t* Bsrc0 = Bseg + dsz(colseg + rS) * K + kg;
  const ushort_t* Bsrc1 = Bseg + dsz(colseg + 64 + rS) * K + kg;
  char* ldsA0 = (char*)sA + tid * 16;
  char* ldsA1 = (char*)sA + 4096 + tid * 16;
  char* ldsB0 = (char*)sB + tid * 16;
  char* ldsB1 = (char*)sB + 4096 + tid * 16;

  for (int k0 = 0; k0 < K; k0 += 32) {
    GL16(Asrc0 + k0, ldsA0);
    GL16(Asrc1 + k0, ldsA1);
    GL16(Bsrc0 + k0, ldsB0);
    GL16(Bsrc1 + k0, ldsB1);
    __syncthreads();

    bf16x8 a[4], b[4];
    #pragma unroll
    for (int m = 0; m < 4; ++m)
      a[m] = *(const bf16x8*)&sA[(wr * 64 + m * 16 + fr) * 32 + fq * 8];
    #pragma unroll
    for (int n = 0; n < 4; ++n)
      b[n] = *(const bf16x8*)&sB[(wc * 64 + n * 16 + fr) * 32 + fq * 8];
    #pragma unroll
    for (int m = 0; m < 4; ++m)
      #pragma unroll
      for (int n = 0; n < 4; ++n)
        acc[m][n] = __builtin_amdgcn_mfma_f32_16x16x32_bf16(a[m], b[n], acc[m][n], 0, 0, 0);
    __syncthreads();
  }

  #pragma unroll
  for (int m = 0; m < 4; ++m)
    #pragma unroll
    for (int n = 0; n < 4; ++n)
      #pragma unroll
      for (int j = 0; j < 4; ++j)
        Cseg[dsz(row0 + wr * 64 + m * 16 + fq * 4 + j) * segN +
             colseg + wc * 64 + n * 16 + fr] = f2bf(acc[m][n][j] * scale);
}

// ---------------------------------------------------------------------------
// Generic bf16 GEMM with f32 output (final Wo projection).
// ---------------------------------------------------------------------------
__global__ __launch_bounds__(256) void gemm_bt_bf16(
    const ushort_t* __restrict__ A, const ushort_t* __restrict__ B,
    float* __restrict__ C, int M, int N, int K)
{
  __shared__ ushort_t sA[128 * 32];
  __shared__ ushort_t sB[128 * 32];

  const int tid  = threadIdx.x;
  const int lane = tid & 63;
  const int wid  = tid >> 6;
  const int wr   = wid >> 1;
  const int wc   = wid & 1;
  const int row0 = blockIdx.y * 128;
  const int col0 = blockIdx.x * 128;
  const int fr = lane & 15;
  const int fq = lane >> 4;

  f32x4 acc[4][4];
  #pragma unroll
  for (int m = 0; m < 4; ++m)
    #pragma unroll
    for (int n = 0; n < 4; ++n) acc[m][n] = (f32x4){0.f, 0.f, 0.f, 0.f};

  const int rS = tid >> 2;
  const int kg = (tid & 3) * 8;
  const ushort_t* Asrc0 = A + dsz(row0 + rS) * K + kg;
  const ushort_t* Asrc1 = A + dsz(row0 + 64 + rS) * K + kg;
  const ushort_t* Bsrc0 = B + dsz(col0 + rS) * K + kg;
  const ushort_t* Bsrc1 = B + dsz(col0 + 64 + rS) * K + kg;
  char* ldsA0 = (char*)sA + tid * 16;
  char* ldsA1 = (char*)sA + 4096 + tid * 16;
  char* ldsB0 = (char*)sB + tid * 16;
  char* ldsB1 = (char*)sB + 4096 + tid * 16;

  for (int k0 = 0; k0 < K; k0 += 32) {
    GL16(Asrc0 + k0, ldsA0);
    GL16(Asrc1 + k0, ldsA1);
    GL16(Bsrc0 + k0, ldsB0);
    GL16(Bsrc1 + k0, ldsB1);
    __syncthreads();

    bf16x8 a[4], b[4];
    #pragma unroll
    for (int m = 0; m < 4; ++m)
      a[m] = *(const bf16x8*)&sA[(wr * 64 + m * 16 + fr) * 32 + fq * 8];
    #pragma unroll
    for (int n = 0; n < 4; ++n)
      b[n] = *(const bf16x8*)&sB[(wc * 64 + n * 16 + fr) * 32 + fq * 8];
    #pragma unroll
    for (int m = 0; m < 4; ++m)
      #pragma unroll
      for (int n = 0; n < 4; ++n)
        acc[m][n] = __builtin_amdgcn_mfma_f32_16x16x32_bf16(a[m], b[n], acc[m][n], 0, 0, 0);
    __syncthreads();
  }

  #pragma unroll
  for (int m = 0; m < 4; ++m)
    #pragma unroll
    for (int n = 0; n < 4; ++n)
      #pragma unroll
      for (int j = 0; j < 4; ++j)
        C[dsz(row0 + wr * 64 + m * 16 + fq * 4 + j) * N +
          col0 + wc * 64 + n * 16 + fr] = acc[m][n][j];
}

// ---------------------------------------------------------------------------
// RoPE in-place on bf16 qb, folds in QSCALE.
// ---------------------------------------------------------------------------
__global__ void rope_q_ip(ushort_t* __restrict__ qb, const int* __restrict__ pos)
{
  int idx = blockIdx.x * blockDim.x + threadIdx.x;   // 2M
  int j = idx & 63;
  int h = (idx >> 6) & 15;
  int r = idx >> 10;
  float p = (float)pos[r];
  float f = p * expf(-(float)j * ROPE_INV);
  float c = cosf(f), s = sinf(f);
  ushort_t* d = qb + dsz(r) * (NHc * HDc) + h * HDc;
  float x1 = bf2f(d[j]), x2 = bf2f(d[j + 64]);
  d[j]      = f2bf((x1 * c - x2 * s) * QSCALE);
  d[j + 64] = f2bf((x2 * c + x1 * s) * QSCALE);
}

// RoPE self-k (bf16 in) -> Kcat rows 1024..2047
__global__ void rope_k_kcat(const ushort_t* __restrict__ kkvb, const int* __restrict__ pos,
                            ushort_t* __restrict__ Kcat)
{
  int idx = blockIdx.x * blockDim.x + threadIdx.x;   // 512K
  int j = idx & 63;
  int kvh = (idx >> 6) & 3;
  int s = (idx >> 8) & 1023;
  int b = idx >> 18;
  float p = (float)pos[b * Sc + s];
  float f = p * expf(-(float)j * ROPE_INV);
  float c = cosf(f), sn = sinf(f);
  const ushort_t* src = kkvb + dsz(b * Sc + s) * (NKVc * HDc) + kvh * HDc;
  ushort_t* dst = Kcat + (dsz(b * NKVc + kvh) * 2048 + 1024 + s) * HDc;
  float x1 = bf2f(src[j]), x2 = bf2f(src[j + 64]);
  dst[j]      = f2bf(x1 * c - x2 * sn);
  dst[j + 64] = f2bf(x2 * c + x1 * sn);
}

// kb_keys fp32 -> Kcat rows 0..1023 bf16
__global__ void kb_kcat(const float* __restrict__ src, ushort_t* __restrict__ Kcat)
{
  int i = blockIdx.x * blockDim.x + threadIdx.x;     // 262144
  int d4 = i & 31;
  int kvh = (i >> 5) & 3;
  int k = (i >> 7) & 1023;
  int b = i >> 17;
  float4 v = *(const float4*)&src[dsz(b * KBc + k) * (NKVc * HDc) + kvh * HDc + d4 * 4];
  ushort4 o;
  o.x = f2bf(v.x); o.y = f2bf(v.y); o.z = f2bf(v.z); o.w = f2bf(v.w);
  *(ushort4*)&Kcat[(dsz(b * NKVc + kvh) * 2048 + k) * HDc + d4 * 4] = o;
}

// Build Vt[b][kvh][128][2048] from kb_values (f32) + vkvb (bf16)
__global__ __launch_bounds__(256) void vt_build(const float* __restrict__ kbv,
                                                const ushort_t* __restrict__ vkvb,
                                                ushort_t* __restrict__ Vt)
{
  __shared__ float sT[32][33];
  const int k0 = blockIdx.x * 32;
  const int d0 = blockIdx.y * 32;
  const int bk = blockIdx.z;
  const int b = bk >> 2, kvh = bk & 3;
  const int tid = threadIdx.x;

  #pragma unroll
  for (int t = 0; t < 4; ++t) {
    int li = tid + t * 256;
    int kk = li >> 5, dl = li & 31;
    int kg = k0 + kk;
    float v = (kg < 1024)
      ? kbv[dsz(b * KBc + kg) * (NKVc * HDc) + kvh * HDc + d0 + dl]
      : bf2f(vkvb[dsz(b * Sc + kg - 1024) * (NKVc * HDc) + kvh * HDc + d0 + dl]);
    sT[kk][dl] = v;
  }
  __syncthreads();
  #pragma unroll
  for (int t = 0; t < 4; ++t) {
    int li = tid + t * 256;
    int dl = li >> 5, kk = li & 31;
    Vt[(dsz(b * NKVc + kvh) * HDc + d0 + dl) * 2048 + k0 + kk] = f2bf(sT[kk][dl]);
  }
}

// ---------------------------------------------------------------------------
// Attention v5: LDS-staged double-buffered (R4 shape: 4 waves x 16q), with
// conflict-free XOR swizzles (R5-verified) and 2-way inter-block KV split.
// Grid (512, 2): block (b,h,qt,half) computes partial (O bf16 unnormalized,
// m/l f32) over its half of the key-tile range; attn_merge combines.
// ---------------------------------------------------------------------------
__global__ __launch_bounds__(256, 4) void attn_mfma5(
    const ushort_t* __restrict__ Qr,   // roped q (pre-scaled), (B*S, 2048)
    const ushort_t* __restrict__ Qn,   // q_new (pre-scaled), (B*S, 2048)
    const ushort_t* __restrict__ Kcat, // (B, NKV, 2048, 128)
    const ushort_t* __restrict__ Vt,   // (B, NKV, 128, 2048)
    ushort_t* __restrict__ Opart,      // [2][512][64][128] bf16
    float* __restrict__ mlpart)        // [2][512][64][2]
{
  __shared__ ushort_t sK[2][32 * 128];   // 8KB/buf, rows XOR-swizzled
  __shared__ ushort_t sV[2][128 * 32];   // 8KB/buf, slots XOR-swizzled

  const int tid = threadIdx.x;
  const int lane = tid & 63;
  const int w = tid >> 6;                // 0..3
  const int fr = lane & 15;
  const int fq = lane >> 4;
  const int blk = blockIdx.x;            // (b,h,qt)
  const int half = blockIdx.y;
  const int qt = blk & 15;
  const int h  = (blk >> 4) & 15;
  const int b  = blk >> 8;
  const int kvh = h >> 2;
  const int qrow = qt * 64 + w * 16 + fr;
  const int kperm = ((fr >> 2) << 3) + (fr & 3);   // u(kperm) = fr

  const ushort_t* Kb = Kcat + dsz(b * NKVc + kvh) * 2048 * HDc;
  const ushort_t* Vb = Vt   + dsz(b * NKVc + kvh) * HDc * 2048;

  const int nt  = 34 + 2 * qt;           // total key tiles (keys=1024+qt*64+64)
  const int mid = nt >> 1;
  const int t_lo = half ? mid : 0;
  const int t_hi = half ? nt  : mid;

  // per-thread staging offsets (swizzle on global source, linear LDS dest)
  const int kr0 = tid >> 4;              // 0..15
  const int ks0 = tid & 15;
  const int ku0 = (kr0 & 3) | ((kr0 >> 3) << 2);
  const int kOffA = kr0 * 256 + ((ks0 ^ ku0) * 16);
  const int kOffB = (kr0 + 16) * 256 + ((ks0 ^ (ku0 + 8)) * 16);
  const int vr0 = tid >> 2;              // 0..63
  const int vs0 = tid & 3;
  const int vu0 = (vr0 >> 1) & 3;
  const size_t vOffA = (size_t)vr0 * 4096 + ((vs0 ^ vu0) * 16);
  const size_t vOffB = vOffA + (size_t)64 * 4096;

  const int vslot = (fq ^ ((fr >> 1) & 3)) * 8;

#define STAGE(bi, t)                                                   \
  {                                                                    \
    const char* kgb = (const char*)Kb + (size_t)(t) * 8192;            \
    const char* vgb = (const char*)Vb + (size_t)(t) * 64;              \
    GL16(kgb + kOffA, (char*)&sK[bi][0] + tid * 16);                   \
    GL16(kgb + kOffB, (char*)&sK[bi][0] + 4096 + tid * 16);            \
    GL16(vgb + vOffA, (char*)&sV[bi][0] + tid * 16);                   \
    GL16(vgb + vOffB, (char*)&sV[bi][0] + 4096 + tid * 16);            \
  }

  // Q fragments for the starting phase
  bf16x8 qf[4];
  {
    const ushort_t* qp = (t_lo >= 32 ? Qr : Qn) + dsz(b * Sc + qrow) * (NHc * HDc) + h * HDc;
    #pragma unroll
    for (int c = 0; c < 4; ++c) qf[c] = *(const bf16x8*)&qp[c * 32 + fq * 8];
  }

  float m = -1e30f, l = 0.f;
  f32x4 ot[8];
  #pragma unroll
  for (int dt = 0; dt < 8; ++dt) ot[dt] = (f32x4){0.f, 0.f, 0.f, 0.f};

  STAGE(0, t_lo);
  __syncthreads();

  for (int t = t_lo; t < t_hi; ++t) {
    const int cur = (t - t_lo) & 1;
    if (t + 1 < t_hi) STAGE(cur ^ 1, t + 1);

    if (t == 32) {   // phase switch: self keys use roped q
      const ushort_t* qp = Qr + dsz(b * Sc + qrow) * (NHc * HDc) + h * HDc;
      #pragma unroll
      for (int c = 0; c < 4; ++c) qf[c] = *(const bf16x8*)&qp[c * 32 + fq * 8];
    }
    const bool self = (t >= 32);

    // fragments from LDS (swizzle undone at read)
    bf16x8 ka0[4], ka1[4], va[8];
    #pragma unroll
    for (int c = 0; c < 4; ++c) {
      const int ks = ((c * 4 + fq) ^ fr) * 8;
      ka0[c] = *(const bf16x8*)&sK[cur][kperm * 128 + ks];
      ka1[c] = *(const bf16x8*)&sK[cur][(kperm + 4) * 128 + ks];
    }
    #pragma unroll
    for (int dt = 0; dt < 8; ++dt)
      va[dt] = *(const bf16x8*)&sV[cur][(dt * 16 + fr) * 32 + vslot];

    f32x4 s0 = (f32x4){0.f, 0.f, 0.f, 0.f};
    f32x4 s1 = (f32x4){0.f, 0.f, 0.f, 0.f};
    #pragma unroll
    for (int c = 0; c < 4; ++c)
      s0 = __builtin_amdgcn_mfma_f32_16x16x32_bf16(ka0[c], qf[c], s0, 0, 0, 0);
    #pragma unroll
    for (int c = 0; c < 4; ++c)
      s1 = __builtin_amdgcn_mfma_f32_16x16x32_bf16(ka1[c], qf[c], s1, 0, 0, 0);

    if (self) {
      #pragma unroll
      for (int j = 0; j < 4; ++j) {
        s0[j] = (t * 32 + fq * 8 + j     - 1024 > qrow) ? -1e30f : s0[j];
        s1[j] = (t * 32 + fq * 8 + 4 + j - 1024 > qrow) ? -1e30f : s1[j];
      }
    }
    float tmax = fmaxf(fmaxf(fmaxf(s0[0], s0[1]), fmaxf(s0[2], s0[3])),
                       fmaxf(fmaxf(s1[0], s1[1]), fmaxf(s1[2], s1[3])));
    tmax = fmaxf(tmax, __shfl_xor(tmax, 16));
    tmax = fmaxf(tmax, __shfl_xor(tmax, 32));

    if (__any(tmax > m + 8.f)) {                 // defer-max (T13)
      float mnew = fmaxf(m, tmax);
      float corr = exp2f(m - mnew);
      l *= corr;
      #pragma unroll
      for (int dt = 0; dt < 8; ++dt) {
        ot[dt][0] *= corr; ot[dt][1] *= corr;
        ot[dt][2] *= corr; ot[dt][3] *= corr;
      }
      m = mnew;
    }
    float ps = 0.f;
    bf16x8 pb;
    #pragma unroll
    for (int j = 0; j < 4; ++j) { float p = exp2f(s0[j] - m); ps += p; pb[j] = (__bf16)p; }
    #pragma unroll
    for (int j = 0; j < 4; ++j) { float p = exp2f(s1[j] - m); ps += p; pb[j + 4] = (__bf16)p; }
    l += ps;

    #pragma unroll
    for (int dt = 0; dt < 8; ++dt)
      ot[dt] = __builtin_amdgcn_mfma_f32_16x16x32_bf16(va[dt], pb, ot[dt], 0, 0, 0);

    __syncthreads();   // drains staging loads; safe buffer swap
  }
#undef STAGE

  // full per-query l (sum over fq lanes)
  l += __shfl_xor(l, 16);
  l += __shfl_xor(l, 32);

  // write partials (O unnormalized bf16; m,l f32)
  const int qin = w * 16 + fr;
  ushort_t* ob = Opart + (dsz(half * 512 + blk) * 64 + qin) * 128;
  #pragma unroll
  for (int dt = 0; dt < 8; ++dt) {
    ushort_t o4a[4];
    #pragma unroll
    for (int j = 0; j < 4; ++j) o4a[j] = f2bf(ot[dt][j]);
    *(ushort4*)&ob[dt * 16 + fq * 4] = *(ushort4*)o4a;
  }
  if (fq == 0) {
    float* mlp = mlpart + (dsz(half * 512 + blk) * 64 + qin) * 2;
    mlp[0] = m;
    mlp[1] = l;
  }
}

// ---------------------------------------------------------------------------
// Merge the 2 KV-split partials -> attnb bf16.
// 2048 blocks x 256 threads x 8 elems = 4M outputs.
// ---------------------------------------------------------------------------
__global__ void attn_merge(const ushort_t* __restrict__ Opart,
                           const float* __restrict__ mlpart,
                           ushort_t* __restrict__ attnb)
{
  const int i = blockIdx.x * 256 + threadIdx.x;    // 8-elem group index
  const int e = i * 8;
  const int qg = e >> 7;          // global (blk512, qin): 0..32767
  const int d0 = e & 127;
  const int blk = qg >> 6;        // 0..511
  const int qin = qg & 63;
  const int qt = blk & 15;
  const int h  = (blk >> 4) & 15;
  const int b  = blk >> 8;

  const float* ml0 = mlpart + dsz(blk) * 128 + qin * 2;
  const float* ml1 = mlpart + dsz(512 + blk) * 128 + qin * 2;
  const float m0 = ml0[0], l0 = ml0[1];
  const float m1 = ml1[0], l1 = ml1[1];
  const float M = fmaxf(m0, m1);
  const float s0 = exp2f(m0 - M), s1 = exp2f(m1 - M);
  const float Linv = 1.f / (l0 * s0 + l1 * s1);
  const float c0 = s0 * Linv, c1 = s1 * Linv;

  const ushort_t* o0 = Opart + (dsz(blk) * 64 + qin) * 128 + d0;
  const ushort_t* o1 = Opart + (dsz(512 + blk) * 64 + qin) * 128 + d0;
  ushort4 a0 = *(const ushort4*)&o0[0];
  ushort4 b0 = *(const ushort4*)&o1[0];
  ushort4 a1 = *(const ushort4*)&o0[4];
  ushort4 b1 = *(const ushort4*)&o1[4];

  ushort_t r[8];
  r[0] = f2bf(bf2f(a0.x) * c0 + bf2f(b0.x) * c1);
  r[1] = f2bf(bf2f(a0.y) * c0 + bf2f(b0.y) * c1);
  r[2] = f2bf(bf2f(a0.z) * c0 + bf2f(b0.z) * c1);
  r[3] = f2bf(bf2f(a0.w) * c0 + bf2f(b0.w) * c1);
  r[4] = f2bf(bf2f(a1.x) * c0 + bf2f(b1.x) * c1);
  r[5] = f2bf(bf2f(a1.y) * c0 + bf2f(b1.y) * c1);
  r[6] = f2bf(bf2f(a1.z) * c0 + bf2f(b1.z) * c1);
  r[7] = f2bf(bf2f(a1.w) * c0 + bf2f(b1.w) * c1);

  ushort_t* dst = attnb + dsz(b * Sc + qt * 64 + qin) * (NHc * HDc) + h * HDc + d0;
  *(ushort4*)&dst[0] = *(ushort4*)&r[0];
  *(ushort4*)&dst[4] = *(ushort4*)&r[4];
}

// ---------------------------------------------------------------------------
// Launch
// ---------------------------------------------------------------------------
extern "C" void kernel_launch(void* const* d_in, const int* in_sizes, int n_in,
                              void* d_out, int out_size, void* d_ws, size_t ws_size,
                              hipStream_t stream)
{
  const float* x    = (const float*)d_in[0];
  const int*   pos  = (const int*)d_in[2];
  const float* kbk  = (const float*)d_in[3];
  const float* kbv  = (const float*)d_in[4];
  const float* Wq   = (const float*)d_in[5];
  const float* Wqn  = (const float*)d_in[6];
  const float* Wk   = (const float*)d_in[7];
  const float* Wv   = (const float*)d_in[8];
  const float* Wo   = (const float*)d_in[9];
  float* out = (float*)d_out;

  const int MR = Bc * Sc;              // 2048
  const size_t MU = 1048576;

  ushort_t* U = (ushort_t*)d_ws;
  ushort_t* xb    = U;                 // 4M u
  ushort_t* Wqb   = U + 4  * MU;       // 4M
  ushort_t* Wqnb  = U + 8  * MU;       // 4M
  ushort_t* Wkb   = U + 12 * MU;       // 1M
  ushort_t* Wvb   = U + 13 * MU;       // 1M
  ushort_t* Wob   = U + 14 * MU;       // 4M
  ushort_t* qb    = U + 18 * MU;       // 4M (roped in-place -> Qr)
  ushort_t* qnb   = U + 22 * MU;       // 4M (pre-scaled)
  ushort_t* kkvb  = U + 26 * MU;       // 1M
  ushort_t* vkvb  = U + 27 * MU;       // 1M
  ushort_t* Kcat  = U + 28 * MU;       // 2M
  ushort_t* Vt    = U + 30 * MU;       // 2M
  ushort_t* attnb = U + 32 * MU;       // 4M  -> total 36M u = 72 MB
  // aliases for attention partials (dead regions at attention time):
  ushort_t* Opart  = U;                        // 8M u (xb+Wqb, dead after gemm_proj)
  float*    mlpart = (float*)(U + 26 * MU);    // 128K f (kkvb, dead after rope_k_kcat)

  dim3 blk(256);

  conv_all<<<18432, blk, 0, stream>>>(x, Wq, Wqn, Wk, Wv, Wo,
                                      xb, Wqb, Wqnb, Wkb, Wvb, Wob);
  gemm_proj<<<dim3(40, 16), blk, 0, stream>>>(xb, Wqb, Wqnb, Wkb, Wvb,
                                              qb, qnb, kkvb, vkvb);
  rope_q_ip<<<8192, blk, 0, stream>>>(qb, pos);
  kb_kcat<<<1024, blk, 0, stream>>>(kbk, Kcat);
  rope_k_kcat<<<2048, blk, 0, stream>>>(kkvb, pos, Kcat);
  vt_build<<<dim3(64, 4, 8), blk, 0, stream>>>(kbv, vkvb, Vt);
  // attention: (b,h,qt) x half grid, 4 waves x 16q, KV-split partials
  attn_mfma5<<<dim3(512, 2), blk, 0, stream>>>(qb, qnb, Kcat, Vt, Opart, mlpart);
  attn_merge<<<2048, blk, 0, stream>>>(Opart, mlpart, attnb);
  gemm_bt_bf16<<<dim3(16, 16), blk, 0, stream>>>(attnb, Wob, out, MR, 2048, Hc);
}